// Round 1
// baseline (101.895 us; speedup 1.0000x reference)
//
#include <hip/hip_runtime.h>
#include <math.h>

#define G 1200
#define BSZ 4
#define NIN 10
#define NHE 300
#define NINC 4800
#define ALPHA 0.005f
#define BETA 5e-5f
#define BN_EPS 1e-5f

__device__ __forceinline__ float eluf(float x) { return x > 0.f ? x : __expf(x) - 1.f; }
__device__ __forceinline__ float sigf(float x) { return 1.f / (1.f + __expf(-x)); }

// K1: h0 = elu(x @ infer_w.T + infer_b); precompute round-1 gate terms a1,c1.
__global__ __launch_bounds__(256)
void infer_kernel(const float* __restrict__ x,
                  const float* __restrict__ infer_w, const float* __restrict__ infer_b,
                  const float* __restrict__ e1w, const float* __restrict__ e1b,
                  float4* __restrict__ xfeat1, float* __restrict__ a1, float* __restrict__ c1) {
    int n = blockIdx.x * blockDim.x + threadIdx.x;
    if (n >= BSZ * G) return;
    const float* xp = x + n * NIN;
    float h[4];
#pragma unroll
    for (int f = 0; f < 4; ++f) {
        float s = infer_b[f];
#pragma unroll
        for (int k = 0; k < NIN; ++k) s += infer_w[f * NIN + k] * xp[k];
        h[f] = eluf(s);
    }
    xfeat1[n] = make_float4(h[0], h[1], h[2], h[3]);
    float av = 0.f, cv = 0.f;
#pragma unroll
    for (int f = 0; f < 4; ++f) { av += e1w[f] * h[f]; cv += e1w[4 + f] * h[f]; }
    a1[n] = av;
    c1[n] = cv + e1b[0];
}

// One block per target gene i; handles all 4 batches so BN (per-gene over 16 vals) fuses.
// MODE 1: round1 -> elu(z*W1diag+b1) -> BN -> store xfeat2 + round2 gate terms.
// MODE 2: round2 -> BN -> store upd2 + xf_bsum[i] = sum_b hg_w @ upd2[b,i].
template <int MODE>
__global__ __launch_bounds__(256)
void round_kernel(const float* __restrict__ edge, float coef,
                  const float4* __restrict__ xfeat,
                  const float* __restrict__ a, const float* __restrict__ c,
                  const float* __restrict__ nw, const float* __restrict__ nb,
                  const float* __restrict__ mw, const float* __restrict__ mb,
                  const float* __restrict__ W1, const float* __restrict__ b1,
                  const float* __restrict__ gw, const float* __restrict__ gb,
                  const float* __restrict__ hgw,
                  float4* __restrict__ out_feat,
                  float* __restrict__ a_out, float* __restrict__ c_out,
                  float4* __restrict__ xf_bsum) {
    const int i = blockIdx.x;
    const int tid = threadIdx.x;
    const float* erow = edge + (size_t)i * G;

    float cb[4];
#pragma unroll
    for (int b = 0; b < 4; ++b) cb[b] = c[b * G + i];

    float acc[20];
#pragma unroll
    for (int k = 0; k < 20; ++k) acc[k] = 0.f;

    for (int j = tid; j < G; j += 256) {
        float m = erow[j];
        float mask = (m == 0.f) ? coef : m;  // edge + coef*(edge==0)
#pragma unroll
        for (int b = 0; b < 4; ++b) {
            float4 xj = xfeat[b * G + j];
            float s = sigf(a[b * G + j] + cb[b]) * mask;
            acc[b * 5 + 0] += s * xj.x;
            acc[b * 5 + 1] += s * xj.y;
            acc[b * 5 + 2] += s * xj.z;
            acc[b * 5 + 3] += s * xj.w;
            acc[b * 5 + 4] += s;
        }
    }

    __shared__ float red[4][20];
    const int lane = tid & 63, wid = tid >> 6;
#pragma unroll
    for (int k = 0; k < 20; ++k) {
        float v = acc[k];
        for (int o = 32; o > 0; o >>= 1) v += __shfl_down(v, o, 64);
        if (lane == 0) red[wid][k] = v;
    }
    __syncthreads();

    if (tid == 0) {
        float t[4][5];
#pragma unroll
        for (int b = 0; b < 4; ++b)
#pragma unroll
            for (int k = 0; k < 5; ++k)
                t[b][k] = red[0][b * 5 + k] + red[1][b * 5 + k] + red[2][b * 5 + k] + red[3][b * 5 + k];

        float w1d = 0.f, b1i = 0.f;
        if (MODE == 1) { w1d = W1[(size_t)i * G + i]; b1i = b1[i]; }

        float hv[4][4];
#pragma unroll
        for (int b = 0; b < 4; ++b) {
            float4 xi4 = xfeat[b * G + i];
            float xi[4] = {xi4.x, xi4.y, xi4.z, xi4.w};
            float ssum = t[b][4];
            float r8[8];
#pragma unroll
            for (int k = 0; k < 4; ++k) { r8[k] = t[b][k]; r8[4 + k] = xi[k] * ssum; }
            float r[4];
#pragma unroll
            for (int f = 0; f < 4; ++f) {
                float s = nb[f];
#pragma unroll
                for (int k = 0; k < 8; ++k) s += nw[f * 8 + k] * r8[k];
                r[f] = eluf(s);
            }
#pragma unroll
            for (int f = 0; f < 4; ++f) {
                float s = mb[f];
#pragma unroll
                for (int k = 0; k < 4; ++k) s += mw[f * 8 + k] * r[k] + mw[f * 8 + 4 + k] * xi[k];
                float z = eluf(s);
                hv[b][f] = (MODE == 1) ? eluf(z * w1d + b1i) : z;
            }
        }

        // BN per gene over (batch, feat): 16 values
        float mean = 0.f;
#pragma unroll
        for (int b = 0; b < 4; ++b)
#pragma unroll
            for (int f = 0; f < 4; ++f) mean += hv[b][f];
        mean *= (1.f / 16.f);
        float var = 0.f;
#pragma unroll
        for (int b = 0; b < 4; ++b)
#pragma unroll
            for (int f = 0; f < 4; ++f) { float d = hv[b][f] - mean; var += d * d; }
        var *= (1.f / 16.f);
        float sc = rsqrtf(var + BN_EPS);
#pragma unroll
        for (int b = 0; b < 4; ++b)
#pragma unroll
            for (int f = 0; f < 4; ++f) hv[b][f] = (hv[b][f] - mean) * sc;

        if (MODE == 1) {
#pragma unroll
            for (int b = 0; b < 4; ++b) {
                out_feat[b * G + i] = make_float4(hv[b][0], hv[b][1], hv[b][2], hv[b][3]);
                float av = 0.f, cv = 0.f;
#pragma unroll
                for (int f = 0; f < 4; ++f) { av += gw[f] * hv[b][f]; cv += gw[4 + f] * hv[b][f]; }
                a_out[b * G + i] = av;
                c_out[b * G + i] = cv + gb[0];
            }
        } else {
            float bs[4] = {0.f, 0.f, 0.f, 0.f};
#pragma unroll
            for (int b = 0; b < 4; ++b) {
                out_feat[b * G + i] = make_float4(hv[b][0], hv[b][1], hv[b][2], hv[b][3]);
#pragma unroll
                for (int f = 0; f < 4; ++f) {
                    float s = 0.f;
#pragma unroll
                    for (int k = 0; k < 4; ++k) s += hgw[f * 4 + k] * hv[b][k];
                    bs[f] += s;
                }
            }
            xf_bsum[i] = make_float4(bs[0], bs[1], bs[2], bs[3]);
        }
    }
}

// K4: hypergraph conv (batch-degenerate: hx identical across batches) + final linear.
// Single block; all accumulators in LDS (~30 KB), zeroed in-kernel (deterministic).
__global__ __launch_bounds__(1024)
void hyper_kernel(const int* __restrict__ nodes, const int* __restrict__ edges,
                  const float4* __restrict__ xf_bsum, const float4* __restrict__ upd2,
                  const float* __restrict__ hgb,
                  const float* __restrict__ m3w, const float* __restrict__ m3b,
                  float4* __restrict__ out) {
    __shared__ int deg[G];
    __shared__ int eh[NHE];
    __shared__ float efeat[NHE][4];
    __shared__ float hxs[G][4];
    const int tid = threadIdx.x;

    for (int t = tid; t < G; t += 1024) {
        deg[t] = 0;
        hxs[t][0] = hxs[t][1] = hxs[t][2] = hxs[t][3] = 0.f;
    }
    for (int t = tid; t < NHE; t += 1024) {
        eh[t] = 0;
        efeat[t][0] = efeat[t][1] = efeat[t][2] = efeat[t][3] = 0.f;
    }
    __syncthreads();

    for (int cI = tid; cI < NINC; cI += 1024) {
        int n = nodes[cI], e = edges[cI];
        atomicAdd(&deg[n], 1);
        atomicAdd(&eh[e], 1);
        float4 v = xf_bsum[n];
        atomicAdd(&efeat[e][0], v.x);
        atomicAdd(&efeat[e][1], v.y);
        atomicAdd(&efeat[e][2], v.z);
        atomicAdd(&efeat[e][3], v.w);
    }
    __syncthreads();

    for (int cI = tid; cI < NINC; cI += 1024) {
        int n = nodes[cI], e = edges[cI];
        float binv = 1.f / (4.f * (float)eh[e]);  // bdeg = B * hist(edges)
        atomicAdd(&hxs[n][0], efeat[e][0] * binv);
        atomicAdd(&hxs[n][1], efeat[e][1] * binv);
        atomicAdd(&hxs[n][2], efeat[e][2] * binv);
        atomicAdd(&hxs[n][3], efeat[e][3] * binv);
    }
    __syncthreads();

    for (int m = tid; m < BSZ * G; m += 1024) {
        int g = m % G;
        float dinv = deg[g] > 0 ? 1.f / (float)deg[g] : 0.f;
        float hxp[4];
#pragma unroll
        for (int f = 0; f < 4; ++f) hxp[f] = eluf(hxs[g][f] * dinv + hgb[f]);
        float4 u4 = upd2[m];
        float u[4] = {u4.x, u4.y, u4.z, u4.w};
        float o[4];
#pragma unroll
        for (int f = 0; f < 4; ++f) {
            float s = m3b[f];
#pragma unroll
            for (int k = 0; k < 4; ++k) s += m3w[f * 8 + k] * u[k] + m3w[f * 8 + 4 + k] * hxp[k];
            o[f] = eluf(s);
        }
        out[m] = make_float4(o[0], o[1], o[2], o[3]);
    }
}

extern "C" void kernel_launch(void* const* d_in, const int* in_sizes, int n_in,
                              void* d_out, int out_size, void* d_ws, size_t ws_size,
                              hipStream_t stream) {
    const float* x       = (const float*)d_in[0];
    const float* edge1   = (const float*)d_in[1];
    const float* edge2   = (const float*)d_in[2];
    const float* W1      = (const float*)d_in[3];
    const float* b1      = (const float*)d_in[4];
    const float* infer_w = (const float*)d_in[5];
    const float* infer_b = (const float*)d_in[6];
    const float* e1w     = (const float*)d_in[7];
    const float* e1b     = (const float*)d_in[8];
    const float* e2w     = (const float*)d_in[9];
    const float* e2b     = (const float*)d_in[10];
    const float* n1w     = (const float*)d_in[11];
    const float* n1b     = (const float*)d_in[12];
    const float* n2w     = (const float*)d_in[13];
    const float* n2b     = (const float*)d_in[14];
    const float* m1w     = (const float*)d_in[15];
    const float* m1b     = (const float*)d_in[16];
    const float* m2w     = (const float*)d_in[17];
    const float* m2b     = (const float*)d_in[18];
    const float* m3w     = (const float*)d_in[19];
    const float* m3b     = (const float*)d_in[20];
    const float* hgw     = (const float*)d_in[21];
    const float* hgb     = (const float*)d_in[22];
    const int*   hn      = (const int*)d_in[23];
    const int*   he      = (const int*)d_in[24];

    char* ws = (char*)d_ws;
    float4* xfeat1 = (float4*)(ws + 0);       // 4800*16 = 76800
    float4* xfeat2 = (float4*)(ws + 76800);   // 76800
    float4* upd2   = (float4*)(ws + 153600);  // 76800
    float4* xfb    = (float4*)(ws + 230400);  // 1200*16 = 19200
    float*  a1     = (float*)(ws + 249600);   // 19200
    float*  c1     = (float*)(ws + 268800);   // 19200
    float*  a2     = (float*)(ws + 288000);   // 19200
    float*  c2     = (float*)(ws + 307200);   // 19200

    infer_kernel<<<(BSZ * G + 255) / 256, 256, 0, stream>>>(x, infer_w, infer_b, e1w, e1b,
                                                            xfeat1, a1, c1);
    round_kernel<1><<<G, 256, 0, stream>>>(edge1, ALPHA, xfeat1, a1, c1, n1w, n1b, m1w, m1b,
                                           W1, b1, e2w, e2b, nullptr,
                                           xfeat2, a2, c2, nullptr);
    round_kernel<2><<<G, 256, 0, stream>>>(edge2, BETA, xfeat2, a2, c2, n2w, n2b, m2w, m2b,
                                           nullptr, nullptr, nullptr, nullptr, hgw,
                                           upd2, nullptr, nullptr, xfb);
    hyper_kernel<<<1, 1024, 0, stream>>>(hn, he, xfb, upd2, hgb, m3w, m3b, (float4*)d_out);
}

// Round 2
// 46.071 us; speedup vs baseline: 2.2117x; 2.2117x over previous
//
#include <hip/hip_runtime.h>
#include <math.h>

#define G 1200
#define BSZ 4
#define NIN 10
#define NHE 300
#define NINC 4800
#define ALPHA 0.005f
#define BETA 5e-5f
#define BN_EPS 1e-5f

__device__ __forceinline__ float eluf(float x) { return x > 0.f ? x : __expf(x) - 1.f; }
__device__ __forceinline__ float sigf(float x) { return 1.f / (1.f + __expf(-x)); }

// K1: h0 = elu(x @ infer_w.T + infer_b); precompute round-1 gate terms a1,c1.
// Block 0 additionally zeros the efeat/eh accumulators used by round2's scatter.
__global__ __launch_bounds__(256)
void infer_kernel(const float* __restrict__ x,
                  const float* __restrict__ infer_w, const float* __restrict__ infer_b,
                  const float* __restrict__ e1w, const float* __restrict__ e1b,
                  float4* __restrict__ xfeat1, float* __restrict__ a1, float* __restrict__ c1,
                  int* __restrict__ zero_region /* 1200 f32 efeat + 300 i32 eh = 1500 words */) {
    if (blockIdx.x == 0) {
        for (int t = threadIdx.x; t < NHE * 4 + NHE * 0 + 1200 + 300 - 1200; t += 256) {}
        for (int t = threadIdx.x; t < 1500; t += 256) zero_region[t] = 0;
    }
    int n = blockIdx.x * blockDim.x + threadIdx.x;
    if (n >= BSZ * G) return;
    const float* xp = x + n * NIN;
    float h[4];
#pragma unroll
    for (int f = 0; f < 4; ++f) {
        float s = infer_b[f];
#pragma unroll
        for (int k = 0; k < NIN; ++k) s += infer_w[f * NIN + k] * xp[k];
        h[f] = eluf(s);
    }
    xfeat1[n] = make_float4(h[0], h[1], h[2], h[3]);
    float av = 0.f, cv = 0.f;
#pragma unroll
    for (int f = 0; f < 4; ++f) { av += e1w[f] * h[f]; cv += e1w[4 + f] * h[f]; }
    a1[n] = av;
    c1[n] = cv + e1b[0];
}

// One block per target gene i; wave w handles batch w (4 waves = 4 batches).
// MODE 1: round1 -> elu(z*W1diag+b1) -> BN -> store xfeat2 + round2 gate terms.
// MODE 2: round2 -> BN -> store upd2; scatter bs = sum_b hg_w@upd2[b,i] into
//         global efeat[e] (+eh histogram) over matching incidences; write deg[i].
template <int MODE>
__global__ __launch_bounds__(256)
void round_kernel(const float* __restrict__ edge, float coef,
                  const float4* __restrict__ xfeat,
                  const float* __restrict__ a, const float* __restrict__ c,
                  const float* __restrict__ nw, const float* __restrict__ nb,
                  const float* __restrict__ mw, const float* __restrict__ mb,
                  const float* __restrict__ W1, const float* __restrict__ b1,
                  const float* __restrict__ gw, const float* __restrict__ gb,
                  const float* __restrict__ hgw,
                  float4* __restrict__ out_feat,
                  float* __restrict__ a_out, float* __restrict__ c_out,
                  const int* __restrict__ hn, const int* __restrict__ he,
                  float* __restrict__ efeat_g, int* __restrict__ eh_g,
                  int* __restrict__ deg_g) {
    const int i = blockIdx.x;
    const int tid = threadIdx.x;
    const int lane = tid & 63;
    const int w = tid >> 6;  // wave index == batch index
    const float* erow = edge + (size_t)i * G;

    const float cb = c[w * G + i];
    float acc0 = 0.f, acc1 = 0.f, acc2 = 0.f, acc3 = 0.f, acc4 = 0.f;

    for (int j = lane; j < G; j += 64) {
        float m = erow[j];
        float mask = (m == 0.f) ? coef : m;  // edge + coef*(edge==0)
        float4 xj = xfeat[w * G + j];
        float s = sigf(a[w * G + j] + cb) * mask;
        acc0 += s * xj.x;
        acc1 += s * xj.y;
        acc2 += s * xj.z;
        acc3 += s * xj.w;
        acc4 += s;
    }
#pragma unroll
    for (int o = 32; o > 0; o >>= 1) {
        acc0 += __shfl_down(acc0, o, 64);
        acc1 += __shfl_down(acc1, o, 64);
        acc2 += __shfl_down(acc2, o, 64);
        acc3 += __shfl_down(acc3, o, 64);
        acc4 += __shfl_down(acc4, o, 64);
    }

    __shared__ float t[4][5];
    __shared__ float hvs[4][4];
    __shared__ float stats[2];
    __shared__ float bss[4][4];
    __shared__ float bsf[4];
    __shared__ int degs;

    if (lane == 0) {
        t[w][0] = acc0; t[w][1] = acc1; t[w][2] = acc2; t[w][3] = acc3; t[w][4] = acc4;
    }
    if (tid == 0) degs = 0;
    __syncthreads();

    if (tid < 4) {
        const int b = tid;
        float4 xi4 = xfeat[b * G + i];
        float xi[4] = {xi4.x, xi4.y, xi4.z, xi4.w};
        float ssum = t[b][4];
        float r8[8];
#pragma unroll
        for (int k = 0; k < 4; ++k) { r8[k] = t[b][k]; r8[4 + k] = xi[k] * ssum; }
        float r[4];
#pragma unroll
        for (int f = 0; f < 4; ++f) {
            float s = nb[f];
#pragma unroll
            for (int k = 0; k < 8; ++k) s += nw[f * 8 + k] * r8[k];
            r[f] = eluf(s);
        }
        float w1d = 0.f, b1i = 0.f;
        if (MODE == 1) { w1d = W1[(size_t)i * G + i]; b1i = b1[i]; }
#pragma unroll
        for (int f = 0; f < 4; ++f) {
            float s = mb[f];
#pragma unroll
            for (int k = 0; k < 4; ++k) s += mw[f * 8 + k] * r[k] + mw[f * 8 + 4 + k] * xi[k];
            float z = eluf(s);
            hvs[b][f] = (MODE == 1) ? eluf(z * w1d + b1i) : z;
        }
    }
    __syncthreads();

    if (tid == 0) {
        float mean = 0.f;
#pragma unroll
        for (int b = 0; b < 4; ++b)
#pragma unroll
            for (int f = 0; f < 4; ++f) mean += hvs[b][f];
        mean *= (1.f / 16.f);
        float var = 0.f;
#pragma unroll
        for (int b = 0; b < 4; ++b)
#pragma unroll
            for (int f = 0; f < 4; ++f) { float d = hvs[b][f] - mean; var += d * d; }
        var *= (1.f / 16.f);
        stats[0] = mean;
        stats[1] = rsqrtf(var + BN_EPS);
    }
    __syncthreads();

    if (tid < 4) {
        const int b = tid;
        const float mean = stats[0], sc = stats[1];
        float hv[4];
#pragma unroll
        for (int f = 0; f < 4; ++f) hv[f] = (hvs[b][f] - mean) * sc;
        out_feat[b * G + i] = make_float4(hv[0], hv[1], hv[2], hv[3]);
        if (MODE == 1) {
            float av = 0.f, cv = 0.f;
#pragma unroll
            for (int f = 0; f < 4; ++f) { av += gw[f] * hv[f]; cv += gw[4 + f] * hv[f]; }
            a_out[b * G + i] = av;
            c_out[b * G + i] = cv + gb[0];
        } else {
#pragma unroll
            for (int f = 0; f < 4; ++f) {
                float s = 0.f;
#pragma unroll
                for (int k = 0; k < 4; ++k) s += hgw[f * 4 + k] * hv[k];
                bss[b][f] = s;
            }
        }
    }

    if (MODE == 2) {
        __syncthreads();
        if (tid < 4) bsf[tid] = bss[0][tid] + bss[1][tid] + bss[2][tid] + bss[3][tid];
        __syncthreads();
        const float b0 = bsf[0], b1v = bsf[1], b2 = bsf[2], b3 = bsf[3];
        int cnt = 0;
        for (int cI = tid; cI < NINC; cI += 256) {
            if (hn[cI] == i) {
                ++cnt;
                int e = he[cI];
                atomicAdd(&eh_g[e], 1);
                atomicAdd(&efeat_g[e * 4 + 0], b0);
                atomicAdd(&efeat_g[e * 4 + 1], b1v);
                atomicAdd(&efeat_g[e * 4 + 2], b2);
                atomicAdd(&efeat_g[e * 4 + 3], b3);
            }
        }
        if (cnt) atomicAdd(&degs, cnt);
        __syncthreads();
        if (tid == 0) deg_g[i] = degs;
    }
}

// K4: block per gene i: gather hx[i] = dinv * sum_{c: nodes[c]==i} efeat[edges[c]]*binv,
// then out[b,i] = elu([upd2[b,i], elu(hx+hgb)] @ m3w.T + m3b) for all 4 batches.
__global__ __launch_bounds__(256)
void final_kernel(const int* __restrict__ hn, const int* __restrict__ he,
                  const float* __restrict__ efeat_g, const int* __restrict__ eh_g,
                  const int* __restrict__ deg_g,
                  const float4* __restrict__ upd2, const float* __restrict__ hgb,
                  const float* __restrict__ m3w, const float* __restrict__ m3b,
                  float4* __restrict__ out) {
    const int i = blockIdx.x;
    const int tid = threadIdx.x;
    const int lane = tid & 63;
    const int w = tid >> 6;

    float a0 = 0.f, a1 = 0.f, a2 = 0.f, a3 = 0.f;
    for (int cI = tid; cI < NINC; cI += 256) {
        if (hn[cI] == i) {
            int e = he[cI];
            float binv = 0.25f / (float)eh_g[e];  // bdeg = BSZ * hist(edges)
            a0 += efeat_g[e * 4 + 0] * binv;
            a1 += efeat_g[e * 4 + 1] * binv;
            a2 += efeat_g[e * 4 + 2] * binv;
            a3 += efeat_g[e * 4 + 3] * binv;
        }
    }
#pragma unroll
    for (int o = 32; o > 0; o >>= 1) {
        a0 += __shfl_down(a0, o, 64);
        a1 += __shfl_down(a1, o, 64);
        a2 += __shfl_down(a2, o, 64);
        a3 += __shfl_down(a3, o, 64);
    }
    __shared__ float red[4][4];
    if (lane == 0) { red[w][0] = a0; red[w][1] = a1; red[w][2] = a2; red[w][3] = a3; }
    __syncthreads();

    if (tid < 4) {
        const int b = tid;
        int dg = deg_g[i];
        float dinv = dg > 0 ? 1.f / (float)dg : 0.f;
        float hxp[4];
#pragma unroll
        for (int f = 0; f < 4; ++f) {
            float hx = (red[0][f] + red[1][f] + red[2][f] + red[3][f]) * dinv;
            hxp[f] = eluf(hx + hgb[f]);
        }
        float4 u4 = upd2[b * G + i];
        float u[4] = {u4.x, u4.y, u4.z, u4.w};
        float o4[4];
#pragma unroll
        for (int f = 0; f < 4; ++f) {
            float s = m3b[f];
#pragma unroll
            for (int k = 0; k < 4; ++k) s += m3w[f * 8 + k] * u[k] + m3w[f * 8 + 4 + k] * hxp[k];
            o4[f] = eluf(s);
        }
        out[b * G + i] = make_float4(o4[0], o4[1], o4[2], o4[3]);
    }
}

extern "C" void kernel_launch(void* const* d_in, const int* in_sizes, int n_in,
                              void* d_out, int out_size, void* d_ws, size_t ws_size,
                              hipStream_t stream) {
    const float* x       = (const float*)d_in[0];
    const float* edge1   = (const float*)d_in[1];
    const float* edge2   = (const float*)d_in[2];
    const float* W1      = (const float*)d_in[3];
    const float* b1      = (const float*)d_in[4];
    const float* infer_w = (const float*)d_in[5];
    const float* infer_b = (const float*)d_in[6];
    const float* e1w     = (const float*)d_in[7];
    const float* e1b     = (const float*)d_in[8];
    const float* e2w     = (const float*)d_in[9];
    const float* e2b     = (const float*)d_in[10];
    const float* n1w     = (const float*)d_in[11];
    const float* n1b     = (const float*)d_in[12];
    const float* n2w     = (const float*)d_in[13];
    const float* n2b     = (const float*)d_in[14];
    const float* m1w     = (const float*)d_in[15];
    const float* m1b     = (const float*)d_in[16];
    const float* m2w     = (const float*)d_in[17];
    const float* m2b     = (const float*)d_in[18];
    const float* m3w     = (const float*)d_in[19];
    const float* m3b     = (const float*)d_in[20];
    const float* hgw     = (const float*)d_in[21];
    const float* hgb     = (const float*)d_in[22];
    const int*   hn      = (const int*)d_in[23];
    const int*   he      = (const int*)d_in[24];

    char* ws = (char*)d_ws;
    float4* xfeat1 = (float4*)(ws + 0);       // 4800*16 = 76800
    float4* xfeat2 = (float4*)(ws + 76800);   // 76800
    float4* upd2   = (float4*)(ws + 153600);  // 76800
    float*  a1     = (float*)(ws + 230400);   // 19200
    float*  c1     = (float*)(ws + 249600);   // 19200
    float*  a2     = (float*)(ws + 268800);   // 19200
    float*  c2     = (float*)(ws + 288000);   // 19200
    float*  efeat  = (float*)(ws + 307200);   // 1200 floats = 4800
    int*    eh     = (int*)(ws + 312000);     // 300 ints = 1200
    int*    deg    = (int*)(ws + 313200);     // 1200 ints = 4800
    // efeat+eh contiguous -> zeroed as 1500 words by infer_kernel block 0

    infer_kernel<<<(BSZ * G + 255) / 256, 256, 0, stream>>>(
        x, infer_w, infer_b, e1w, e1b, xfeat1, a1, c1, (int*)efeat);
    round_kernel<1><<<G, 256, 0, stream>>>(
        edge1, ALPHA, xfeat1, a1, c1, n1w, n1b, m1w, m1b, W1, b1, e2w, e2b, nullptr,
        xfeat2, a2, c2, nullptr, nullptr, nullptr, nullptr, nullptr);
    round_kernel<2><<<G, 256, 0, stream>>>(
        edge2, BETA, xfeat2, a2, c2, n2w, n2b, m2w, m2b, nullptr, nullptr, nullptr, nullptr, hgw,
        upd2, nullptr, nullptr, hn, he, efeat, eh, deg);
    final_kernel<<<G, 256, 0, stream>>>(
        hn, he, efeat, eh, deg, upd2, hgb, m3w, m3b, (float4*)d_out);
}